// Round 1
// baseline (98.514 us; speedup 1.0000x reference)
//
#include <hip/hip_runtime.h>

// Problem constants (from reference): B=8, L=2048, H=1024, C=64
#define PB 8
#define PL 2048
#define PH 1024
#define PC 64

// Kernel 1: s[b*L + l] = dot(feature[b,l,:], w)
// One wave (64 lanes) per row; each lane handles 16 contiguous-by-lane floats
// via 4x float4 loads (coalesced: lane i reads row[j*256 + i*4 .. +3]).
__global__ __launch_bounds__(256) void row_dot_kernel(
    const float* __restrict__ feature,   // [B*L, H]
    const float* __restrict__ w,         // [H]
    float* __restrict__ s)               // [B*L]
{
    const int gtid = blockIdx.x * 256 + threadIdx.x;
    const int row  = gtid >> 6;          // global wave id = row index
    const int lane = threadIdx.x & 63;

    const float* rp = feature + (size_t)row * PH;

    float acc = 0.0f;
#pragma unroll
    for (int j = 0; j < PH / 256; ++j) {
        const int idx = j * 256 + lane * 4;
        float4 f = *reinterpret_cast<const float4*>(rp + idx);
        float4 g = *reinterpret_cast<const float4*>(w + idx);
        acc += f.x * g.x + f.y * g.y + f.z * g.z + f.w * g.w;
    }

    // wave64 butterfly reduce
#pragma unroll
    for (int off = 32; off > 0; off >>= 1)
        acc += __shfl_down(acc, off, 64);

    if (lane == 0) s[row] = acc;
}

// Kernel 2: per (b,c) span, mean of s[b, src..end] + bias.
// One wave per span (B*C = 512 spans).
__global__ __launch_bounds__(256) void span_pool_kernel(
    const float* __restrict__ s,         // [B, L]
    const int* __restrict__ pos,         // [B, C, 2] (src, end) inclusive
    const float* __restrict__ bias,      // [1]
    float* __restrict__ out)             // [B*C]
{
    const int gtid = blockIdx.x * 256 + threadIdx.x;
    const int span = gtid >> 6;          // 0..B*C-1
    const int lane = threadIdx.x & 63;

    const int b   = span / PC;
    const int src = pos[span * 2 + 0];
    const int end = pos[span * 2 + 1];

    const float* sb = s + b * PL;
    float acc = 0.0f;
    for (int l = src + lane; l <= end; l += 64)
        acc += sb[l];

#pragma unroll
    for (int off = 32; off > 0; off >>= 1)
        acc += __shfl_down(acc, off, 64);

    if (lane == 0) {
        const float cnt = (float)(end - src + 1);  // src<=end guaranteed, cnt>=1
        out[span] = acc / cnt + bias[0];
    }
}

extern "C" void kernel_launch(void* const* d_in, const int* in_sizes, int n_in,
                              void* d_out, int out_size, void* d_ws, size_t ws_size,
                              hipStream_t stream) {
    const float* feature = (const float*)d_in[0];   // [B, L, H] fp32
    const float* fc_w    = (const float*)d_in[1];   // [1, H]
    const float* fc_b    = (const float*)d_in[2];   // [1]
    const int*   pos     = (const int*)d_in[3];     // [B, C, 2] int32
    float*       out     = (float*)d_out;           // [B*C, 1] fp32
    float*       s       = (float*)d_ws;            // B*L floats = 64 KB scratch

    // Kernel 1: B*L = 16384 rows, 1 wave/row, 4 waves/block -> 4096 blocks
    row_dot_kernel<<<(PB * PL) / 4, 256, 0, stream>>>(feature, fc_w, s);

    // Kernel 2: B*C = 512 spans, 1 wave/span -> 128 blocks
    span_pool_kernel<<<(PB * PC * 64) / 256, 256, 0, stream>>>(s, pos, fc_b, out);
}